// Round 7
// baseline (559.148 us; speedup 1.0000x reference)
//
#include <hip/hip_runtime.h>
#include <hip/hip_bf16.h>
#include <math.h>

// Problem constants (fixed by the reference)
#define B_SZ   4096
#define D      64
#define RPB    8192                 // rows per branch = 2*B
#define NCHUNK 16                   // column chunks (blockIdx.x)
#define TPC    4                    // 128-col tiles per chunk
#define NPART  32                   // partials per row = NCHUNK * 2 (wn halves)
#define LN2    0.69314718055994531f
#define PRESCALE 2.6857914f         // sqrt(5*log2(e)); X pre-scaled: Gram = base-2 logits

typedef __attribute__((ext_vector_type(8))) short  bf16x8;
typedef __attribute__((ext_vector_type(4))) float  f32x4;

__device__ __forceinline__ float fexp2(float x) { return __builtin_amdgcn_exp2f(x); }

// ws layout:
//   Xbf  : 2*8192*64 bf16   = 2 MB  (pre-scaled by PRESCALE)
//   dots : 8192 float       = 32 KB (v1_i . v2_i, unscaled fp32)
//   P    : 2*8192*32 float2 = 4 MB  (per-row per-(chunk,wn) (m,s), base-2; user m=0)

// ---------------------------------------------------------------------------
__global__ __launch_bounds__(256) void gather_kernel(
    const int* __restrict__ u_idx, const int* __restrict__ i_idx,
    const float* __restrict__ u1e, const float* __restrict__ i1e,
    const float* __restrict__ u2e, const float* __restrict__ i2e,
    __hip_bfloat16* __restrict__ Xbf, float* __restrict__ dots)
{
    const int tid  = threadIdx.x;
    const int wave = tid >> 6, lane = tid & 63;
    const int g      = blockIdx.x * 4 + wave;   // 0..8191
    const int branch = g >> 12;
    const int i      = g & (B_SZ - 1);
    const int idx    = (branch == 0) ? u_idx[i] : i_idx[i];
    const float* s1  = (branch == 0) ? u1e : i1e;
    const float* s2  = (branch == 0) ? u2e : i2e;

    float v1 = s1[(size_t)idx * D + lane];
    float v2 = s2[(size_t)idx * D + lane];
    if (branch == 0) {
        float a = v1 * v1, b = v2 * v2;
        #pragma unroll
        for (int o = 32; o > 0; o >>= 1) {
            a += __shfl_xor(a, o, 64);
            b += __shfl_xor(b, o, 64);
        }
        v1 *= rsqrtf(a);
        v2 *= rsqrtf(b);
    }
    float p = v1 * v2;
    #pragma unroll
    for (int o = 32; o > 0; o >>= 1) p += __shfl_xor(p, o, 64);
    if (lane == 0) dots[g] = p;

    const size_t row1 = (size_t)branch * RPB + i;
    Xbf[row1 * D + lane]          = __float2bfloat16(v1 * PRESCALE);
    Xbf[(row1 + B_SZ) * D + lane] = __float2bfloat16(v2 * PRESCALE);
}

// ---------------------------------------------------------------------------
// One 128-row x (TPC*128)-col gram unit + per-lane online logsumexp (base-2).
// IS_USER=1: logits bounded (|y|<=7.3) -> no max tracking, plain exp2-sum.
template<int IS_USER>
__device__ __forceinline__ void gram_body(
    const __hip_bfloat16* __restrict__ Xb, float2* __restrict__ P,
    __hip_bfloat16 (&Bs)[128][72], int bx, int chunk, int tid)
{
    const int r0   = bx * 128;
    const int wave = tid >> 6, lane = tid & 63;
    const int wm = wave >> 1, wn = wave & 1;
    const int quad = lane >> 4, tx = lane & 15;

    // Stage A panel through Bs, hoist A fragments to registers (K=64 fits).
    #pragma unroll
    for (int p = 0; p < 4; ++p) {
        int e = p * 256 + tid;
        int row = e >> 3, c8 = e & 7;
        *(uint4*)&Bs[row][c8 * 8] =
            *(const uint4*)(Xb + (size_t)(r0 + row) * D + c8 * 8);
    }
    __syncthreads();
    bf16x8 afr[4][2];
    #pragma unroll
    for (int mt = 0; mt < 4; ++mt)
        #pragma unroll
        for (int ks = 0; ks < 2; ++ks)
            afr[mt][ks] = *(const bf16x8*)&Bs[wm * 64 + mt * 16 + tx][ks * 32 + quad * 8];

    float m_run[16], s_run[16];
    #pragma unroll
    for (int r = 0; r < 16; ++r) { m_run[r] = -INFINITY; s_run[r] = 0.f; }

    const int lrq  = wm * 64 + quad * 4;
    const int lcol = wn * 64 + tx;

    for (int t = 0; t < TPC; ++t) {
        const int ct = chunk * TPC + t;
        const int c0 = ct * 128;
        __syncthreads();                // afr reads (t=0) / prior B-frag reads done
        #pragma unroll
        for (int p = 0; p < 4; ++p) {
            int e = p * 256 + tid;
            int row = e >> 3, c8 = e & 7;
            *(uint4*)&Bs[row][c8 * 8] =
                *(const uint4*)(Xb + (size_t)(c0 + row) * D + c8 * 8);
        }
        __syncthreads();

        f32x4 acc[4][4];
        const f32x4 z = {0.f, 0.f, 0.f, 0.f};
        #pragma unroll
        for (int nt = 0; nt < 4; ++nt) {
            const bf16x8 b0 = *(const bf16x8*)&Bs[wn * 64 + nt * 16 + tx][quad * 8];
            #pragma unroll
            for (int mt = 0; mt < 4; ++mt)
                acc[mt][nt] = __builtin_amdgcn_mfma_f32_16x16x32_bf16(afr[mt][0], b0, z, 0, 0, 0);
        }
        #pragma unroll
        for (int nt = 0; nt < 4; ++nt) {
            const bf16x8 b1 = *(const bf16x8*)&Bs[wn * 64 + nt * 16 + tx][32 + quad * 8];
            #pragma unroll
            for (int mt = 0; mt < 4; ++mt)
                acc[mt][nt] = __builtin_amdgcn_mfma_f32_16x16x32_bf16(afr[mt][1], b1, acc[mt][nt], 0, 0, 0);
        }

        const bool diag = (ct == bx);
        #pragma unroll
        for (int mt = 0; mt < 4; ++mt) {
            #pragma unroll
            for (int rr = 0; rr < 4; ++rr) {
                float y0 = acc[mt][0][rr], y1 = acc[mt][1][rr],
                      y2 = acc[mt][2][rr], y3 = acc[mt][3][rr];
                if (diag) {              // acc already = base-2 logits (pre-scaled X)
                    const int dr = lrq + mt * 16 + rr - lcol;
                    if (dr == 0)  y0 = -INFINITY;
                    if (dr == 16) y1 = -INFINITY;
                    if (dr == 32) y2 = -INFINITY;
                    if (dr == 48) y3 = -INFINITY;
                }
                const int r = mt * 4 + rr;
                if (IS_USER) {
                    s_run[r] += fexp2(y0) + fexp2(y1) + fexp2(y2) + fexp2(y3);
                } else {
                    float mx   = fmaxf(fmaxf(y0, y1), fmaxf(y2, y3));
                    float newm = fmaxf(m_run[r], mx);
                    s_run[r] = s_run[r] * fexp2(m_run[r] - newm)
                             + fexp2(y0 - newm) + fexp2(y1 - newm)
                             + fexp2(y2 - newm) + fexp2(y3 - newm);
                    m_run[r] = newm;
                }
            }
        }
    }

    // Merge across the 16 tx lanes of this wave; (row, chunk, wn) own slot.
    #pragma unroll
    for (int r = 0; r < 16; ++r) {
        float m = IS_USER ? 0.f : m_run[r];
        float s = s_run[r];
        #pragma unroll
        for (int o = 1; o < 16; o <<= 1) {
            if (IS_USER) {
                s += __shfl_xor(s, o, 64);
            } else {
                float om = __shfl_xor(m, o, 64);
                float os = __shfl_xor(s, o, 64);
                float M  = fmaxf(m, om);
                s = s * fexp2(m - M) + os * fexp2(om - M);
                m = M;
            }
        }
        if (tx == 0) {
            const int grow = r0 + wm * 64 + (r >> 2) * 16 + quad * 4 + (r & 3);
            P[(size_t)grow * NPART + chunk * 2 + wn] = make_float2(m, s);
        }
    }
}

// ---------------------------------------------------------------------------
// Both branches, one launch: grid (NCHUNK, 64, 2) = 2048 blocks.
// VGPR=64, LDS 18.4 KB -> 8 blocks/CU co-resident (launch_bounds(256,8)),
// exactly one dispatch round. 2x the waves/CU of R6 to cover barrier stalls.
__global__ __launch_bounds__(256, 8) void gram_lse_kernel(
    const __hip_bfloat16* __restrict__ Xbf, float2* __restrict__ P)
{
    __shared__ __align__(16) __hip_bfloat16 Bs[128][72];  // +8 pad -> ~2-way (free)
    const int chunk = blockIdx.x, bx = blockIdx.y, bz = blockIdx.z;
    if (bz == 0)
        gram_body<1>(Xbf, P, Bs, bx, chunk, threadIdx.x);
    else
        gram_body<0>(Xbf + (size_t)RPB * D, P + (size_t)RPB * NPART,
                     Bs, bx, chunk, threadIdx.x);
}

// ---------------------------------------------------------------------------
// Merge the 32 per-row partials -> lse -> reduce; fold in the positive-pair
// correction from dots[]. grid = 2048 x 256 (each block: 8 rows, 4 dots).
__global__ __launch_bounds__(256) void merge_kernel(
    const float2* __restrict__ P, const float* __restrict__ dots,
    float* __restrict__ out)
{
    __shared__ float red[4];
    const int tid  = threadIdx.x;
    const int wave = tid >> 6, lane = tid & 63;
    const int row  = (blockIdx.x * 4 + wave) * 2 + (lane >> 5);  // 0..16383
    const int c    = lane & 31;

    float2 p = P[(size_t)row * NPART + c];
    float m = p.x, s = p.y;
    #pragma unroll
    for (int o = 1; o < 32; o <<= 1) {             // online merge across 32 lanes
        float om = __shfl_xor(m, o, 64);
        float os = __shfl_xor(s, o, 64);
        float M  = fmaxf(m, om);
        s = s * fexp2(m - M) + os * fexp2(om - M);
        m = M;
    }

    float v = 0.f;
    if ((lane & 31) == 0)
        v = LN2 * (m + log2f(s)) * (1.0f / (float)RPB);   // lse_row / (2B)
    if (tid < 4)                                           // positive-pair correction
        v -= dots[blockIdx.x * 4 + tid] * (5.0f / (float)B_SZ);

    #pragma unroll
    for (int o = 32; o > 0; o >>= 1) v += __shfl_xor(v, o, 64);
    if (lane == 0) red[wave] = v;
    __syncthreads();
    if (tid == 0)
        atomicAdd(out, red[0] + red[1] + red[2] + red[3]);
}

// ---------------------------------------------------------------------------
extern "C" void kernel_launch(void* const* d_in, const int* in_sizes, int n_in,
                              void* d_out, int out_size, void* d_ws, size_t ws_size,
                              hipStream_t stream) {
    const int*   u_idx = (const int*)d_in[0];
    const int*   i_idx = (const int*)d_in[1];
    const float* u1e   = (const float*)d_in[2];
    const float* i1e   = (const float*)d_in[3];
    const float* u2e   = (const float*)d_in[4];
    const float* i2e   = (const float*)d_in[5];
    float* out = (float*)d_out;

    __hip_bfloat16* Xbf = (__hip_bfloat16*)d_ws;                  // 2 MB
    float*  dots = (float*)((char*)d_ws + 2 * RPB * D * 2);       // 32 KB
    float2* P    = (float2*)((char*)dots + RPB * sizeof(float));  // 4 MB

    hipMemsetAsync(out, 0, sizeof(float), stream);

    gather_kernel<<<dim3(2048), dim3(256), 0, stream>>>(
        u_idx, i_idx, u1e, i1e, u2e, i2e, Xbf, dots);
    gram_lse_kernel<<<dim3(NCHUNK, 64, 2), dim3(256), 0, stream>>>(Xbf, P);
    merge_kernel<<<dim3(2048), dim3(256), 0, stream>>>(P, dots, out);
}

// Round 8
// 189.863 us; speedup vs baseline: 2.9450x; 2.9450x over previous
//
#include <hip/hip_runtime.h>
#include <hip/hip_bf16.h>
#include <math.h>

// Problem constants (fixed by the reference)
#define B_SZ   4096
#define D      64
#define RPB    8192                 // rows per branch = 2*B
#define NCHUNK 8                    // col chunks per strip (= partials per row)
#define TPW    16                   // 64-col tiles per wave (128 tiles / 8 chunks)
#define LN2    0.69314718055994531f
#define PRESCALE 2.6857914f         // sqrt(5*log2(e)); X pre-scaled: Gram = base-2 logits

typedef __attribute__((ext_vector_type(8))) short  bf16x8;
typedef __attribute__((ext_vector_type(4))) float  f32x4;

__device__ __forceinline__ float fexp2(float x) { return __builtin_amdgcn_exp2f(x); }

// ws layout:
//   Xbf  : 2*8192*64 bf16  = 2 MB  (pre-scaled; fits every XCD's 4 MB L2)
//   dots : 8192 float      = 32 KB (v1_i . v2_i, unscaled fp32)
//   P    : 2*8192*8 float2 = 1 MB  (per-row per-chunk (m,s), base-2; user m=0)

// ---------------------------------------------------------------------------
__global__ __launch_bounds__(256) void gather_kernel(
    const int* __restrict__ u_idx, const int* __restrict__ i_idx,
    const float* __restrict__ u1e, const float* __restrict__ i1e,
    const float* __restrict__ u2e, const float* __restrict__ i2e,
    __hip_bfloat16* __restrict__ Xbf, float* __restrict__ dots)
{
    const int tid  = threadIdx.x;
    const int wave = tid >> 6, lane = tid & 63;
    const int g      = blockIdx.x * 4 + wave;   // 0..8191
    const int branch = g >> 12;
    const int i      = g & (B_SZ - 1);
    const int idx    = (branch == 0) ? u_idx[i] : i_idx[i];
    const float* s1  = (branch == 0) ? u1e : i1e;
    const float* s2  = (branch == 0) ? u2e : i2e;

    float v1 = s1[(size_t)idx * D + lane];
    float v2 = s2[(size_t)idx * D + lane];
    if (branch == 0) {
        float a = v1 * v1, b = v2 * v2;
        #pragma unroll
        for (int o = 32; o > 0; o >>= 1) {
            a += __shfl_xor(a, o, 64);
            b += __shfl_xor(b, o, 64);
        }
        v1 *= rsqrtf(a);
        v2 *= rsqrtf(b);
    }
    float p = v1 * v2;
    #pragma unroll
    for (int o = 32; o > 0; o >>= 1) p += __shfl_xor(p, o, 64);
    if (lane == 0) dots[g] = p;

    const size_t row1 = (size_t)branch * RPB + i;
    Xbf[row1 * D + lane]          = __float2bfloat16(v1 * PRESCALE);
    Xbf[(row1 + B_SZ) * D + lane] = __float2bfloat16(v2 * PRESCALE);
}

// ---------------------------------------------------------------------------
// LDS-free gram strip: each wave owns a 32-row strip x 1024 cols (16 tiles
// of 32x64), loading A/B MFMA fragments DIRECTLY from global (X is 2 MB,
// L2-resident). No __syncthreads, no staging. Loop order per tile:
// MFMA(bfr) -> issue next bfr loads -> long epilogue (hides L2 latency).
// IS_USER=1: logits bounded (|y|<=7.3) -> no max tracking.
template<int IS_USER>
__device__ __forceinline__ void gram_body(
    const __hip_bfloat16* __restrict__ Xb, float2* __restrict__ P,
    int strip, int chunk, int lane)
{
    const int quad = lane >> 4, tx = lane & 15;
    const int r0   = strip * 32;
    const int voff = tx * D + quad * 8;       // per-lane fragment offset (elems)

    // A fragments: 2 mt x 2 ks, 16B aligned dwordx4 each.
    bf16x8 afr[2][2];
    {
        const __hip_bfloat16* pa = Xb + (size_t)r0 * D + voff;
        #pragma unroll
        for (int mt = 0; mt < 2; ++mt)
            #pragma unroll
            for (int ks = 0; ks < 2; ++ks)
                afr[mt][ks] = *(const bf16x8*)(pa + mt * 16 * D + ks * 32);
    }

    float m_run[8], s_run[8];
    #pragma unroll
    for (int r = 0; r < 8; ++r) { m_run[r] = -INFINITY; s_run[r] = 0.f; }

    const int c0_0 = chunk * TPW * 64;
    const __hip_bfloat16* pb = Xb + (size_t)c0_0 * D + voff;

    // Preload B fragments for tile 0.
    bf16x8 bfr[4][2];
    #pragma unroll
    for (int nt = 0; nt < 4; ++nt)
        #pragma unroll
        for (int ks = 0; ks < 2; ++ks)
            bfr[nt][ks] = *(const bf16x8*)(pb + nt * 16 * D + ks * 32);

    for (int t = 0; t < TPW; ++t) {
        const int c0 = c0_0 + t * 64;

        // 16 MFMAs (2 mt x 4 nt x 2 ks), first ks takes C=0.
        f32x4 acc[2][4];
        const f32x4 z = {0.f, 0.f, 0.f, 0.f};
        #pragma unroll
        for (int nt = 0; nt < 4; ++nt)
            #pragma unroll
            for (int mt = 0; mt < 2; ++mt)
                acc[mt][nt] = __builtin_amdgcn_mfma_f32_16x16x32_bf16(
                    afr[mt][0], bfr[nt][0], z, 0, 0, 0);
        #pragma unroll
        for (int nt = 0; nt < 4; ++nt)
            #pragma unroll
            for (int mt = 0; mt < 2; ++mt)
                acc[mt][nt] = __builtin_amdgcn_mfma_f32_16x16x32_bf16(
                    afr[mt][1], bfr[nt][1], acc[mt][nt], 0, 0, 0);

        // Issue next tile's B loads now; epilogue below hides their latency.
        if (t + 1 < TPW) {
            const __hip_bfloat16* pn = pb + (size_t)(t + 1) * 64 * D;
            #pragma unroll
            for (int nt = 0; nt < 4; ++nt)
                #pragma unroll
                for (int ks = 0; ks < 2; ++ks)
                    bfr[nt][ks] = *(const bf16x8*)(pn + nt * 16 * D + ks * 32);
        }

        // Epilogue: mask Gram diagonal, per-lane online logsumexp (base-2).
        const bool diag = (r0 >= c0) && (r0 < c0 + 64);
        #pragma unroll
        for (int mt = 0; mt < 2; ++mt) {
            #pragma unroll
            for (int rr = 0; rr < 4; ++rr) {
                float y0 = acc[mt][0][rr], y1 = acc[mt][1][rr],
                      y2 = acc[mt][2][rr], y3 = acc[mt][3][rr];
                if (diag) {              // acc already = base-2 logits
                    const int dd = (r0 - c0) + mt * 16 + quad * 4 + rr - tx;
                    if (dd == 0)  y0 = -INFINITY;
                    if (dd == 16) y1 = -INFINITY;
                    if (dd == 32) y2 = -INFINITY;
                    if (dd == 48) y3 = -INFINITY;
                }
                const int r = mt * 4 + rr;
                if (IS_USER) {
                    s_run[r] += fexp2(y0) + fexp2(y1) + fexp2(y2) + fexp2(y3);
                } else {
                    float mx   = fmaxf(fmaxf(y0, y1), fmaxf(y2, y3));
                    float newm = fmaxf(m_run[r], mx);
                    s_run[r] = s_run[r] * fexp2(m_run[r] - newm)
                             + fexp2(y0 - newm) + fexp2(y1 - newm)
                             + fexp2(y2 - newm) + fexp2(y3 - newm);
                    m_run[r] = newm;
                }
            }
        }
    }

    // Merge across the 16 tx lanes; write (row, chunk) partial.
    #pragma unroll
    for (int r = 0; r < 8; ++r) {
        float m = IS_USER ? 0.f : m_run[r];
        float s = s_run[r];
        #pragma unroll
        for (int o = 1; o < 16; o <<= 1) {
            if (IS_USER) {
                s += __shfl_xor(s, o, 64);
            } else {
                float om = __shfl_xor(m, o, 64);
                float os = __shfl_xor(s, o, 64);
                float M  = fmaxf(m, om);
                s = s * fexp2(m - M) + os * fexp2(om - M);
                m = M;
            }
        }
        if (tx == 0) {
            const int row = r0 + (r >> 2) * 16 + quad * 4 + (r & 3);
            P[(size_t)row * NCHUNK + chunk] = make_float2(m, s);
        }
    }
}

// ---------------------------------------------------------------------------
// grid (NCHUNK, 64, 2) = 1024 blocks; block = 4 waves = 4 strips.
// No LDS -> occupancy limited only by registers (~120 -> 4 waves/SIMD).
__global__ __launch_bounds__(256, 4) void gram_kernel(
    const __hip_bfloat16* __restrict__ Xbf, float2* __restrict__ P)
{
    const int tid  = threadIdx.x;
    const int wave = tid >> 6, lane = tid & 63;
    const int strip = blockIdx.y * 4 + wave;   // 0..255 (32-row strips)
    const int chunk = blockIdx.x;
    if (blockIdx.z == 0)
        gram_body<1>(Xbf, P, strip, chunk, lane);
    else
        gram_body<0>(Xbf + (size_t)RPB * D, P + (size_t)RPB * NCHUNK,
                     strip, chunk, lane);
}

// ---------------------------------------------------------------------------
// Merge the 8 per-row partials -> lse -> reduce; fold positive-pair dots.
// grid = 512 x 256 (block: 32 rows, 16 dots).
__global__ __launch_bounds__(256) void merge_kernel(
    const float2* __restrict__ P, const float* __restrict__ dots,
    float* __restrict__ out)
{
    __shared__ float red[4];
    const int tid  = threadIdx.x;
    const int wave = tid >> 6, lane = tid & 63;
    const int row  = (blockIdx.x * 4 + wave) * 8 + (lane >> 3);  // 0..16383
    const int c    = lane & 7;

    float2 p = P[(size_t)row * NCHUNK + c];
    float m = p.x, s = p.y;
    #pragma unroll
    for (int o = 1; o < 8; o <<= 1) {              // online merge across 8 lanes
        float om = __shfl_xor(m, o, 64);
        float os = __shfl_xor(s, o, 64);
        float M  = fmaxf(m, om);
        s = s * fexp2(m - M) + os * fexp2(om - M);
        m = M;
    }

    float v = 0.f;
    if ((lane & 7) == 0)
        v = LN2 * (m + log2f(s)) * (1.0f / (float)RPB);   // lse_row / (2B)
    if (tid < 16)                                          // positive-pair corr
        v -= dots[blockIdx.x * 16 + tid] * (5.0f / (float)B_SZ);

    #pragma unroll
    for (int o = 32; o > 0; o >>= 1) v += __shfl_xor(v, o, 64);
    if (lane == 0) red[wave] = v;
    __syncthreads();
    if (tid == 0)
        atomicAdd(out, red[0] + red[1] + red[2] + red[3]);
}

// ---------------------------------------------------------------------------
extern "C" void kernel_launch(void* const* d_in, const int* in_sizes, int n_in,
                              void* d_out, int out_size, void* d_ws, size_t ws_size,
                              hipStream_t stream) {
    const int*   u_idx = (const int*)d_in[0];
    const int*   i_idx = (const int*)d_in[1];
    const float* u1e   = (const float*)d_in[2];
    const float* i1e   = (const float*)d_in[3];
    const float* u2e   = (const float*)d_in[4];
    const float* i2e   = (const float*)d_in[5];
    float* out = (float*)d_out;

    __hip_bfloat16* Xbf = (__hip_bfloat16*)d_ws;                  // 2 MB
    float*  dots = (float*)((char*)d_ws + 2 * RPB * D * 2);       // 32 KB
    float2* P    = (float2*)((char*)dots + RPB * sizeof(float));  // 1 MB

    hipMemsetAsync(out, 0, sizeof(float), stream);

    gather_kernel<<<dim3(2048), dim3(256), 0, stream>>>(
        u_idx, i_idx, u1e, i1e, u2e, i2e, Xbf, dots);
    gram_kernel<<<dim3(NCHUNK, 64, 2), dim3(256), 0, stream>>>(Xbf, P);
    merge_kernel<<<dim3(512), dim3(256), 0, stream>>>(P, dots, out);
}